// Round 4
// baseline (957.682 us; speedup 1.0000x reference)
//
#include <hip/hip_runtime.h>
#include <hip/hip_bf16.h>
#include <math.h>

#define N_NODES 50000
#define N_EDGES 800000
#define ET_EDGES (N_EDGES + N_NODES)   // with self-loops
#define CH 64
#define NEG_SLOPE 0.2f
#define NBLK ((N_NODES + 255) / 256)   // 196 scan blocks

typedef __hip_bfloat16 bf16;

__device__ inline float bfbits(unsigned short u) {
    return __uint_as_float(((unsigned)u) << 16);
}

// ---------------- dtype detection ----------------
__global__ void detect_dtype(const unsigned short* __restrict__ w1raw,
                             unsigned* __restrict__ flag)
{
    int t = threadIdx.x;
    float v0 = bfbits(w1raw[2 * t]);
    float v1 = bfbits(w1raw[2 * t + 1]);
    bool bad = !(fabsf(v0) <= 64.f && fabsf(v1) <= 64.f);  // NaN -> bad
    unsigned long long b = __ballot(bad);
    if (t == 0) *flag = (b == 0ull) ? 1u : 0u;
}

// ---------------- param conversion (12 small tensors -> fp32) ----------------
struct CvtArgs {
    const void* src[12];
    float*      dst[12];
    int         n[12];
};

__global__ __launch_bounds__(256)
void convert_params(CvtArgs a, const unsigned* __restrict__ flag)
{
    bool isbf = (*flag != 0u);
    int which = blockIdx.y;
    int n = a.n[which];
    const void* s = a.src[which];
    float* d = a.dst[which];
    for (int i = blockIdx.x * 256 + threadIdx.x; i < n; i += gridDim.x * 256) {
        d[i] = isbf ? bfbits(((const unsigned short*)s)[i])
                    : ((const float*)s)[i];
    }
}

// ---------------- CSR build ----------------
__global__ __launch_bounds__(256)
void edge_hist(const int* __restrict__ ei, int* __restrict__ deg)
{
    int e = blockIdx.x * 256 + threadIdx.x;
    if (e >= ET_EDGES) return;
    int d = (e < N_EDGES) ? ei[N_EDGES + e] : e - N_EDGES;
    atomicAdd(&deg[d], 1);
}

__global__ __launch_bounds__(256)
void scan1(const int* __restrict__ deg, int* __restrict__ bsum)
{
    __shared__ int s[256];
    int i = blockIdx.x * 256 + threadIdx.x;
    s[threadIdx.x] = (i < N_NODES) ? deg[i] : 0;
    __syncthreads();
    for (int off = 128; off > 0; off >>= 1) {
        if (threadIdx.x < off) s[threadIdx.x] += s[threadIdx.x + off];
        __syncthreads();
    }
    if (threadIdx.x == 0) bsum[blockIdx.x] = s[0];
}

__global__ void scan2(int* __restrict__ bsum)
{
    if (threadIdx.x == 0) {
        int acc = 0;
        for (int i = 0; i < NBLK; ++i) { int t = bsum[i]; bsum[i] = acc; acc += t; }
    }
}

__global__ __launch_bounds__(256)
void scan3(const int* __restrict__ deg, const int* __restrict__ bsum,
           int* __restrict__ rowptr, int* __restrict__ cursor)
{
    __shared__ int s[256];
    int i = blockIdx.x * 256 + threadIdx.x;
    int v = (i < N_NODES) ? deg[i] : 0;
    s[threadIdx.x] = v;
    __syncthreads();
    for (int off = 1; off < 256; off <<= 1) {
        int t = (threadIdx.x >= off) ? s[threadIdx.x - off] : 0;
        __syncthreads();
        s[threadIdx.x] += t;
        __syncthreads();
    }
    if (i < N_NODES) {
        int excl = s[threadIdx.x] - v + bsum[blockIdx.x];
        rowptr[i] = excl;
        cursor[i] = excl;
    }
    if (i == 0) rowptr[N_NODES] = ET_EDGES;
}

__global__ __launch_bounds__(256)
void edge_fill(const int* __restrict__ ei, int* __restrict__ cursor,
               int* __restrict__ csr_src)
{
    int e = blockIdx.x * 256 + threadIdx.x;
    if (e >= ET_EDGES) return;
    int s, d;
    if (e < N_EDGES) { s = ei[e]; d = ei[N_EDGES + e]; }
    else             { s = d = e - N_EDGES; }
    int pos = atomicAdd(&cursor[d], 1);
    csr_src[pos] = s;
}

// ---------------- GEMM + alpha epilogue (32 rows/block, 8 rows/thread) ------
// block = 256 (4 waves). lane = output col; wave w owns rows w*8..w*8+7.
// Per 4-k step: 4 lane-varying b32 W reads (2-way bank alias = free) +
// 8 broadcast b128 x reads + 32 FMAs.
template<int CIN, bool DYN>
__global__ __launch_bounds__(256)
void gemm_alpha(const void* __restrict__ x,
                const float* __restrict__ W,
                const float* __restrict__ a_src,
                const float* __restrict__ a_dst,
                const unsigned* __restrict__ flag,
                float* __restrict__ h,
                float* __restrict__ as_out,
                float* __restrict__ ad_out)
{
    __shared__ float sW[CIN * 64];
    __shared__ float sx[32 * CIN];
    const bool isbf = DYN ? (*flag != 0u) : false;
    const int tid = threadIdx.x;
    const int col = tid & 63;
    const int wv  = tid >> 6;
    const int row0 = blockIdx.x * 32;

    // stage W (fp32, contiguous, float4)
    for (int i = tid * 4; i < CIN * 64; i += 1024)
        *(float4*)&sW[i] = *(const float4*)&W[i];

    // stage x tile: rows row0..row0+31 are one contiguous span of 32*CIN elems
    const long xbase = (long)row0 * CIN;
    const int  tile  = 32 * CIN;
    const int  limit = (N_NODES - row0) * CIN;   // multiple of 4
    if (DYN && isbf) {
        const unsigned short* xb = (const unsigned short*)x + xbase;
        for (int i = tid * 4; i < tile; i += 1024) {
            float4 v = {0.f, 0.f, 0.f, 0.f};
            if (i < limit) {
                ushort4 u = *(const ushort4*)&xb[i];
                v.x = bfbits(u.x); v.y = bfbits(u.y);
                v.z = bfbits(u.z); v.w = bfbits(u.w);
            }
            *(float4*)&sx[i] = v;
        }
    } else {
        const float* xf = (const float*)x + xbase;
        for (int i = tid * 4; i < tile; i += 1024) {
            float4 v = {0.f, 0.f, 0.f, 0.f};
            if (i < limit) v = *(const float4*)&xf[i];
            *(float4*)&sx[i] = v;
        }
    }
    __syncthreads();

    const int rbase = wv * 8;
    float acc[8];
#pragma unroll
    for (int r = 0; r < 8; ++r) acc[r] = 0.f;

#pragma unroll
    for (int kk = 0; kk < CIN; kk += 4) {
        float w0 = sW[(kk + 0) * 64 + col];
        float w1 = sW[(kk + 1) * 64 + col];
        float w2 = sW[(kk + 2) * 64 + col];
        float w3 = sW[(kk + 3) * 64 + col];
#pragma unroll
        for (int r = 0; r < 8; ++r) {
            const float4 xv = *(const float4*)&sx[(rbase + r) * CIN + kk];
            acc[r] = fmaf(xv.x, w0,
                     fmaf(xv.y, w1,
                     fmaf(xv.z, w2,
                     fmaf(xv.w, w3, acc[r]))));
        }
    }

    const float sa = a_src[col];
    const float sd = a_dst[col];
#pragma unroll
    for (int r = 0; r < 8; ++r) {
        int row = row0 + rbase + r;
        float vs = acc[r] * sa;
        float vd = acc[r] * sd;
#pragma unroll
        for (int off = 32; off > 0; off >>= 1) {
            vs += __shfl_xor(vs, off, 64);
            vd += __shfl_xor(vd, off, 64);
        }
        if (row < N_NODES) {
            h[(long)row * 64 + col] = acc[r];
            if (col == 0) { as_out[row] = vs; ad_out[row] = vd; }
        }
    }
}

// ---------------- Fused GAT gather: softmax + weighted sum + bias(+ELU) ----
template<bool DO_ELU, bool OUT_DYN>
__global__ __launch_bounds__(256)
void gat_gather(const int* __restrict__ rowptr,
                const int* __restrict__ csr_src,
                const float* __restrict__ as_,
                const float* __restrict__ ad_,
                const float* __restrict__ h,
                const float* __restrict__ bias,
                void* __restrict__ out,
                const unsigned* __restrict__ flag)
{
    int node = blockIdx.x * 4 + (threadIdx.x >> 6);
    if (node >= N_NODES) return;
    int lane = threadIdx.x & 63;
    int beg = rowptr[node];
    int deg = rowptr[node + 1] - beg;
    float adv = ad_[node];

    int   my_src = 0;
    float my_e   = -1e30f;
    if (lane < deg) {
        my_src = csr_src[beg + lane];
        float v = as_[my_src] + adv;
        my_e = (v > 0.f) ? v : NEG_SLOPE * v;
    }
    float m = my_e;
    for (int j = 64 + lane; j < deg; j += 64) {
        int s2 = csr_src[beg + j];
        float v = as_[s2] + adv;
        v = (v > 0.f) ? v : NEG_SLOPE * v;
        m = fmaxf(m, v);
    }
#pragma unroll
    for (int off = 32; off > 0; off >>= 1) m = fmaxf(m, __shfl_xor(m, off, 64));

    float w = (lane < deg) ? __expf(my_e - m) : 0.f;
    float dsum = w;
    for (int j = 64 + lane; j < deg; j += 64) {
        int s2 = csr_src[beg + j];
        float v = as_[s2] + adv;
        v = (v > 0.f) ? v : NEG_SLOPE * v;
        dsum += __expf(v - m);
    }
#pragma unroll
    for (int off = 32; off > 0; off >>= 1) dsum += __shfl_xor(dsum, off, 64);
    float inv = 1.f / dsum;

    float acc = 0.f;
    int dmin = (deg < 64) ? deg : 64;
    for (int j = 0; j < dmin; ++j) {
        float wj = __shfl(w, j, 64);
        int   sj = __shfl(my_src, j, 64);
        acc += wj * h[(long)sj * 64 + lane];
    }
    for (int j = 64; j < deg; ++j) {          // rare (deg > 64)
        int sj = csr_src[beg + j];
        float v = as_[sj] + adv;
        v = (v > 0.f) ? v : NEG_SLOPE * v;
        acc += __expf(v - m) * h[(long)sj * 64 + lane];
    }
    acc = acc * inv + bias[lane];
    if (DO_ELU) acc = (acc > 0.f) ? acc : expm1f(acc);
    long oidx = (long)node * 64 + lane;
    if (OUT_DYN && *flag != 0u) ((bf16*)out)[oidx] = __float2bfloat16(acc);
    else                        ((float*)out)[oidx] = acc;
}

extern "C" void kernel_launch(void* const* d_in, const int* in_sizes, int n_in,
                              void* d_out, int out_size, void* d_ws, size_t ws_size,
                              hipStream_t stream)
{
    const void* x  = d_in[0];
    const int*  ei = (const int*)d_in[1];
    const void* pW1 = d_in[2],  *pas1 = d_in[3],  *pad1 = d_in[4],  *pb1 = d_in[5];
    const void* pW2 = d_in[6],  *pas2 = d_in[7],  *pad2 = d_in[8],  *pb2 = d_in[9];
    const void* pW3 = d_in[10], *pas3 = d_in[11], *pad3 = d_in[12], *pb3 = d_in[13];

    float* ws = (float*)d_ws;
    float*    bufA   = ws;                          // h (GEMM out)      12.8 MB
    float*    bufB   = bufA + (long)N_NODES * 64;   // layer io          12.8 MB
    float*    as_    = bufB + (long)N_NODES * 64;   // 200 KB
    float*    ad_    = as_ + N_NODES;
    int*      deg    = (int*)(ad_ + N_NODES);       // 200 KB
    int*      rowptr = deg + N_NODES;               // 200 KB (+1)
    int*      cursor = rowptr + N_NODES + 1;        // 200 KB
    int*      bsum   = cursor + N_NODES;            // 196
    int*      csr_src= bsum + NBLK;                 // 3.4 MB
    float*    prm    = (float*)(csr_src + ET_EDGES);
    unsigned* flag   = (unsigned*)(prm + 20000);

    float* W1 = prm;     float* as1 = W1 + 8192; float* ad1 = as1 + 64; float* b1 = ad1 + 64;
    float* W2 = b1 + 64; float* as2 = W2 + 4096; float* ad2 = as2 + 64; float* b2 = ad2 + 64;
    float* W3 = b2 + 64; float* as3 = W3 + 4096; float* ad3 = as3 + 64; float* b3 = ad3 + 64;

    detect_dtype<<<1, 64, 0, stream>>>((const unsigned short*)pW1, flag);

    CvtArgs ca;
    const void* srcs[12] = {pW1, pas1, pad1, pb1, pW2, pas2, pad2, pb2, pW3, pas3, pad3, pb3};
    float*      dsts[12] = {W1, as1, ad1, b1, W2, as2, ad2, b2, W3, as3, ad3, b3};
    int         ns[12]   = {8192, 64, 64, 64, 4096, 64, 64, 64, 4096, 64, 64, 64};
    for (int i = 0; i < 12; ++i) { ca.src[i] = srcs[i]; ca.dst[i] = dsts[i]; ca.n[i] = ns[i]; }
    convert_params<<<dim3(8, 12), 256, 0, stream>>>(ca, flag);

    // ---- CSR build (once per launch, shared by all 3 layers) ----
    const int edge_grid = (ET_EDGES + 255) / 256;
    hipMemsetAsync(deg, 0, (size_t)N_NODES * 4, stream);
    edge_hist<<<edge_grid, 256, 0, stream>>>(ei, deg);
    scan1<<<NBLK, 256, 0, stream>>>(deg, bsum);
    scan2<<<1, 64, 0, stream>>>(bsum);
    scan3<<<NBLK, 256, 0, stream>>>(deg, bsum, rowptr, cursor);
    edge_fill<<<edge_grid, 256, 0, stream>>>(ei, cursor, csr_src);

    const int gemm_grid = (N_NODES + 31) / 32;
    const int gat_grid  = (N_NODES + 3) / 4;

    // ---------- Layer 1 ----------
    gemm_alpha<128, true><<<gemm_grid, 256, 0, stream>>>(
        x, W1, as1, ad1, flag, bufA, as_, ad_);
    gat_gather<true, false><<<gat_grid, 256, 0, stream>>>(
        rowptr, csr_src, as_, ad_, bufA, b1, bufB, flag);

    // ---------- Layer 2 ----------
    gemm_alpha<64, false><<<gemm_grid, 256, 0, stream>>>(
        bufB, W2, as2, ad2, flag, bufA, as_, ad_);
    gat_gather<true, false><<<gat_grid, 256, 0, stream>>>(
        rowptr, csr_src, as_, ad_, bufA, b2, bufB, flag);

    // ---------- Layer 3 ----------
    gemm_alpha<64, false><<<gemm_grid, 256, 0, stream>>>(
        bufB, W3, as3, ad3, flag, bufA, as_, ad_);
    gat_gather<false, true><<<gat_grid, 256, 0, stream>>>(
        rowptr, csr_src, as_, ad_, bufA, b3, d_out, flag);
}

// Round 5
// 460.529 us; speedup vs baseline: 2.0795x; 2.0795x over previous
//
#include <hip/hip_runtime.h>
#include <hip/hip_bf16.h>
#include <math.h>

#define N_NODES 50000
#define N_EDGES 800000
#define ET_EDGES (N_EDGES + N_NODES)   // with self-loops
#define CH 64
#define NEG_SLOPE 0.2f
#define NBLK ((N_NODES + 255) / 256)   // 196 scan blocks

typedef __hip_bfloat16 bf16;

__device__ inline float bfbits(unsigned short u) {
    return __uint_as_float(((unsigned)u) << 16);
}

// ---------------- dtype detection ----------------
__global__ void detect_dtype(const unsigned short* __restrict__ w1raw,
                             unsigned* __restrict__ flag)
{
    int t = threadIdx.x;
    float v0 = bfbits(w1raw[2 * t]);
    float v1 = bfbits(w1raw[2 * t + 1]);
    bool bad = !(fabsf(v0) <= 64.f && fabsf(v1) <= 64.f);  // NaN -> bad
    unsigned long long b = __ballot(bad);
    if (t == 0) *flag = (b == 0ull) ? 1u : 0u;
}

// ---------------- param conversion (12 small tensors -> fp32) ----------------
struct CvtArgs {
    const void* src[12];
    float*      dst[12];
    int         n[12];
};

__global__ __launch_bounds__(256)
void convert_params(CvtArgs a, const unsigned* __restrict__ flag)
{
    bool isbf = (*flag != 0u);
    int which = blockIdx.y;
    int n = a.n[which];
    const void* s = a.src[which];
    float* d = a.dst[which];
    for (int i = blockIdx.x * 256 + threadIdx.x; i < n; i += gridDim.x * 256) {
        d[i] = isbf ? bfbits(((const unsigned short*)s)[i])
                    : ((const float*)s)[i];
    }
}

// ---------------- CSR build ----------------
__global__ __launch_bounds__(256)
void edge_hist(const int* __restrict__ ei, int* __restrict__ deg)
{
    int e = blockIdx.x * 256 + threadIdx.x;
    if (e >= ET_EDGES) return;
    int d = (e < N_EDGES) ? ei[N_EDGES + e] : e - N_EDGES;
    atomicAdd(&deg[d], 1);
}

__global__ __launch_bounds__(256)
void scan1(const int* __restrict__ deg, int* __restrict__ bsum)
{
    __shared__ int s[256];
    int i = blockIdx.x * 256 + threadIdx.x;
    s[threadIdx.x] = (i < N_NODES) ? deg[i] : 0;
    __syncthreads();
    for (int off = 128; off > 0; off >>= 1) {
        if (threadIdx.x < off) s[threadIdx.x] += s[threadIdx.x + off];
        __syncthreads();
    }
    if (threadIdx.x == 0) bsum[blockIdx.x] = s[0];
}

__global__ void scan2(int* __restrict__ bsum)
{
    if (threadIdx.x == 0) {
        int acc = 0;
        for (int i = 0; i < NBLK; ++i) { int t = bsum[i]; bsum[i] = acc; acc += t; }
    }
}

__global__ __launch_bounds__(256)
void scan3(const int* __restrict__ deg, const int* __restrict__ bsum,
           int* __restrict__ rowptr, int* __restrict__ cursor)
{
    __shared__ int s[256];
    int i = blockIdx.x * 256 + threadIdx.x;
    int v = (i < N_NODES) ? deg[i] : 0;
    s[threadIdx.x] = v;
    __syncthreads();
    for (int off = 1; off < 256; off <<= 1) {
        int t = (threadIdx.x >= off) ? s[threadIdx.x - off] : 0;
        __syncthreads();
        s[threadIdx.x] += t;
        __syncthreads();
    }
    if (i < N_NODES) {
        int excl = s[threadIdx.x] - v + bsum[blockIdx.x];
        rowptr[i] = excl;
        cursor[i] = excl;
    }
    if (i == 0) rowptr[N_NODES] = ET_EDGES;
}

__global__ __launch_bounds__(256)
void edge_fill(const int* __restrict__ ei, int* __restrict__ cursor,
               int* __restrict__ csr_src)
{
    int e = blockIdx.x * 256 + threadIdx.x;
    if (e >= ET_EDGES) return;
    int s, d;
    if (e < N_EDGES) { s = ei[e]; d = ei[N_EDGES + e]; }
    else             { s = d = e - N_EDGES; }
    int pos = atomicAdd(&cursor[d], 1);
    csr_src[pos] = s;
}

// ---------------- GEMM + alpha epilogue (32 rows/block, 8 rows/thread) ------
// block = 256 (4 waves). lane = output col; wave w owns rows w*8..w*8+7.
// k-loop unroll CAPPED at 2: full unroll (round 4) spilled 256 VGPRs ->
// 1.3 GB/dispatch scratch traffic. unroll-2 keeps ~8+8+4 live floats.
template<int CIN, bool DYN>
__global__ __launch_bounds__(256)
void gemm_alpha(const void* __restrict__ x,
                const float* __restrict__ W,
                const float* __restrict__ a_src,
                const float* __restrict__ a_dst,
                const unsigned* __restrict__ flag,
                float* __restrict__ h,
                float* __restrict__ as_out,
                float* __restrict__ ad_out)
{
    __shared__ float sW[CIN * 64];
    __shared__ float sx[32 * CIN];
    const bool isbf = DYN ? (*flag != 0u) : false;
    const int tid = threadIdx.x;
    const int col = tid & 63;
    const int wv  = tid >> 6;
    const int row0 = blockIdx.x * 32;

    // stage W (fp32, contiguous, float4)
    for (int i = tid * 4; i < CIN * 64; i += 1024)
        *(float4*)&sW[i] = *(const float4*)&W[i];

    // stage x tile: rows row0..row0+31 are one contiguous span of 32*CIN elems
    const long xbase = (long)row0 * CIN;
    const int  tile  = 32 * CIN;
    const int  limit = (N_NODES - row0) * CIN;   // multiple of 4
    if (DYN && isbf) {
        const unsigned short* xb = (const unsigned short*)x + xbase;
        for (int i = tid * 4; i < tile; i += 1024) {
            float4 v = {0.f, 0.f, 0.f, 0.f};
            if (i < limit) {
                ushort4 u = *(const ushort4*)&xb[i];
                v.x = bfbits(u.x); v.y = bfbits(u.y);
                v.z = bfbits(u.z); v.w = bfbits(u.w);
            }
            *(float4*)&sx[i] = v;
        }
    } else {
        const float* xf = (const float*)x + xbase;
        for (int i = tid * 4; i < tile; i += 1024) {
            float4 v = {0.f, 0.f, 0.f, 0.f};
            if (i < limit) v = *(const float4*)&xf[i];
            *(float4*)&sx[i] = v;
        }
    }
    __syncthreads();

    const int rbase = wv * 8;
    float acc[8];
#pragma unroll
    for (int r = 0; r < 8; ++r) acc[r] = 0.f;

#pragma unroll 2
    for (int kk = 0; kk < CIN; kk += 4) {
        float w0 = sW[(kk + 0) * 64 + col];
        float w1 = sW[(kk + 1) * 64 + col];
        float w2 = sW[(kk + 2) * 64 + col];
        float w3 = sW[(kk + 3) * 64 + col];
#pragma unroll
        for (int r = 0; r < 8; ++r) {
            const float4 xv = *(const float4*)&sx[(rbase + r) * CIN + kk];
            acc[r] = fmaf(xv.x, w0,
                     fmaf(xv.y, w1,
                     fmaf(xv.z, w2,
                     fmaf(xv.w, w3, acc[r]))));
        }
    }

    const float sa = a_src[col];
    const float sd = a_dst[col];
#pragma unroll
    for (int r = 0; r < 8; ++r) {
        int row = row0 + rbase + r;
        float vs = acc[r] * sa;
        float vd = acc[r] * sd;
#pragma unroll
        for (int off = 32; off > 0; off >>= 1) {
            vs += __shfl_xor(vs, off, 64);
            vd += __shfl_xor(vd, off, 64);
        }
        if (row < N_NODES) {
            h[(long)row * 64 + col] = acc[r];
            if (col == 0) { as_out[row] = vs; ad_out[row] = vd; }
        }
    }
}

// ---------------- Fused GAT gather: softmax + weighted sum + bias(+ELU) ----
template<bool DO_ELU, bool OUT_DYN>
__global__ __launch_bounds__(256)
void gat_gather(const int* __restrict__ rowptr,
                const int* __restrict__ csr_src,
                const float* __restrict__ as_,
                const float* __restrict__ ad_,
                const float* __restrict__ h,
                const float* __restrict__ bias,
                void* __restrict__ out,
                const unsigned* __restrict__ flag)
{
    int node = blockIdx.x * 4 + (threadIdx.x >> 6);
    if (node >= N_NODES) return;
    int lane = threadIdx.x & 63;
    int beg = rowptr[node];
    int deg = rowptr[node + 1] - beg;
    float adv = ad_[node];

    int   my_src = 0;
    float my_e   = -1e30f;
    if (lane < deg) {
        my_src = csr_src[beg + lane];
        float v = as_[my_src] + adv;
        my_e = (v > 0.f) ? v : NEG_SLOPE * v;
    }
    float m = my_e;
    for (int j = 64 + lane; j < deg; j += 64) {
        int s2 = csr_src[beg + j];
        float v = as_[s2] + adv;
        v = (v > 0.f) ? v : NEG_SLOPE * v;
        m = fmaxf(m, v);
    }
#pragma unroll
    for (int off = 32; off > 0; off >>= 1) m = fmaxf(m, __shfl_xor(m, off, 64));

    float w = (lane < deg) ? __expf(my_e - m) : 0.f;
    float dsum = w;
    for (int j = 64 + lane; j < deg; j += 64) {
        int s2 = csr_src[beg + j];
        float v = as_[s2] + adv;
        v = (v > 0.f) ? v : NEG_SLOPE * v;
        dsum += __expf(v - m);
    }
#pragma unroll
    for (int off = 32; off > 0; off >>= 1) dsum += __shfl_xor(dsum, off, 64);
    float inv = 1.f / dsum;

    float acc = 0.f;
    int dmin = (deg < 64) ? deg : 64;
    for (int j = 0; j < dmin; ++j) {
        float wj = __shfl(w, j, 64);
        int   sj = __shfl(my_src, j, 64);
        acc += wj * h[(long)sj * 64 + lane];
    }
    for (int j = 64; j < deg; ++j) {          // rare (deg > 64)
        int sj = csr_src[beg + j];
        float v = as_[sj] + adv;
        v = (v > 0.f) ? v : NEG_SLOPE * v;
        acc += __expf(v - m) * h[(long)sj * 64 + lane];
    }
    acc = acc * inv + bias[lane];
    if (DO_ELU) acc = (acc > 0.f) ? acc : expm1f(acc);
    long oidx = (long)node * 64 + lane;
    if (OUT_DYN && *flag != 0u) ((bf16*)out)[oidx] = __float2bfloat16(acc);
    else                        ((float*)out)[oidx] = acc;
}

extern "C" void kernel_launch(void* const* d_in, const int* in_sizes, int n_in,
                              void* d_out, int out_size, void* d_ws, size_t ws_size,
                              hipStream_t stream)
{
    const void* x  = d_in[0];
    const int*  ei = (const int*)d_in[1];
    const void* pW1 = d_in[2],  *pas1 = d_in[3],  *pad1 = d_in[4],  *pb1 = d_in[5];
    const void* pW2 = d_in[6],  *pas2 = d_in[7],  *pad2 = d_in[8],  *pb2 = d_in[9];
    const void* pW3 = d_in[10], *pas3 = d_in[11], *pad3 = d_in[12], *pb3 = d_in[13];

    float* ws = (float*)d_ws;
    float*    bufA   = ws;                          // h (GEMM out)      12.8 MB
    float*    bufB   = bufA + (long)N_NODES * 64;   // layer io          12.8 MB
    float*    as_    = bufB + (long)N_NODES * 64;   // 200 KB
    float*    ad_    = as_ + N_NODES;
    int*      deg    = (int*)(ad_ + N_NODES);       // 200 KB
    int*      rowptr = deg + N_NODES;               // 200 KB (+1)
    int*      cursor = rowptr + N_NODES + 1;        // 200 KB
    int*      bsum   = cursor + N_NODES;            // 196
    int*      csr_src= bsum + NBLK;                 // 3.4 MB
    float*    prm    = (float*)(csr_src + ET_EDGES);
    unsigned* flag   = (unsigned*)(prm + 20000);

    float* W1 = prm;     float* as1 = W1 + 8192; float* ad1 = as1 + 64; float* b1 = ad1 + 64;
    float* W2 = b1 + 64; float* as2 = W2 + 4096; float* ad2 = as2 + 64; float* b2 = ad2 + 64;
    float* W3 = b2 + 64; float* as3 = W3 + 4096; float* ad3 = as3 + 64; float* b3 = ad3 + 64;

    detect_dtype<<<1, 64, 0, stream>>>((const unsigned short*)pW1, flag);

    CvtArgs ca;
    const void* srcs[12] = {pW1, pas1, pad1, pb1, pW2, pas2, pad2, pb2, pW3, pas3, pad3, pb3};
    float*      dsts[12] = {W1, as1, ad1, b1, W2, as2, ad2, b2, W3, as3, ad3, b3};
    int         ns[12]   = {8192, 64, 64, 64, 4096, 64, 64, 64, 4096, 64, 64, 64};
    for (int i = 0; i < 12; ++i) { ca.src[i] = srcs[i]; ca.dst[i] = dsts[i]; ca.n[i] = ns[i]; }
    convert_params<<<dim3(8, 12), 256, 0, stream>>>(ca, flag);

    // ---- CSR build (once per launch, shared by all 3 layers) ----
    const int edge_grid = (ET_EDGES + 255) / 256;
    hipMemsetAsync(deg, 0, (size_t)N_NODES * 4, stream);
    edge_hist<<<edge_grid, 256, 0, stream>>>(ei, deg);
    scan1<<<NBLK, 256, 0, stream>>>(deg, bsum);
    scan2<<<1, 64, 0, stream>>>(bsum);
    scan3<<<NBLK, 256, 0, stream>>>(deg, bsum, rowptr, cursor);
    edge_fill<<<edge_grid, 256, 0, stream>>>(ei, cursor, csr_src);

    const int gemm_grid = (N_NODES + 31) / 32;
    const int gat_grid  = (N_NODES + 3) / 4;

    // ---------- Layer 1 ----------
    gemm_alpha<128, true><<<gemm_grid, 256, 0, stream>>>(
        x, W1, as1, ad1, flag, bufA, as_, ad_);
    gat_gather<true, false><<<gat_grid, 256, 0, stream>>>(
        rowptr, csr_src, as_, ad_, bufA, b1, bufB, flag);

    // ---------- Layer 2 ----------
    gemm_alpha<64, false><<<gemm_grid, 256, 0, stream>>>(
        bufB, W2, as2, ad2, flag, bufA, as_, ad_);
    gat_gather<true, false><<<gat_grid, 256, 0, stream>>>(
        rowptr, csr_src, as_, ad_, bufA, b2, bufB, flag);

    // ---------- Layer 3 ----------
    gemm_alpha<64, false><<<gemm_grid, 256, 0, stream>>>(
        bufB, W3, as3, ad3, flag, bufA, as_, ad_);
    gat_gather<false, true><<<gat_grid, 256, 0, stream>>>(
        rowptr, csr_src, as_, ad_, bufA, b3, d_out, flag);
}

// Round 6
// 378.345 us; speedup vs baseline: 2.5312x; 1.2172x over previous
//
#include <hip/hip_runtime.h>
#include <hip/hip_bf16.h>
#include <math.h>

#define N_NODES 50000
#define N_EDGES 800000
#define ET_EDGES (N_EDGES + N_NODES)   // with self-loops
#define CH 64
#define NEG_SLOPE 0.2f
#define NBLK ((N_NODES + 255) / 256)   // 196 scan blocks

typedef __hip_bfloat16 bf16;

__device__ inline float bfbits(unsigned short u) {
    return __uint_as_float(((unsigned)u) << 16);
}
__device__ inline float bflo(unsigned u) { return __uint_as_float(u << 16); }
__device__ inline float bfhi(unsigned u) { return __uint_as_float(u & 0xffff0000u); }

// ---------------- dtype detection ----------------
__global__ void detect_dtype(const unsigned short* __restrict__ w1raw,
                             unsigned* __restrict__ flag)
{
    int t = threadIdx.x;
    float v0 = bfbits(w1raw[2 * t]);
    float v1 = bfbits(w1raw[2 * t + 1]);
    bool bad = !(fabsf(v0) <= 64.f && fabsf(v1) <= 64.f);  // NaN -> bad
    unsigned long long b = __ballot(bad);
    if (t == 0) *flag = (b == 0ull) ? 1u : 0u;
}

// ---------------- param conversion (12 small tensors -> fp32) ----------------
struct CvtArgs {
    const void* src[12];
    float*      dst[12];
    int         n[12];
};

__global__ __launch_bounds__(256)
void convert_params(CvtArgs a, const unsigned* __restrict__ flag)
{
    bool isbf = (*flag != 0u);
    int which = blockIdx.y;
    int n = a.n[which];
    const void* s = a.src[which];
    float* d = a.dst[which];
    for (int i = blockIdx.x * 256 + threadIdx.x; i < n; i += gridDim.x * 256) {
        d[i] = isbf ? bfbits(((const unsigned short*)s)[i])
                    : ((const float*)s)[i];
    }
}

// ---------------- CSR build ----------------
__global__ __launch_bounds__(256)
void edge_hist(const int* __restrict__ ei, int* __restrict__ deg)
{
    int e = blockIdx.x * 256 + threadIdx.x;
    if (e >= ET_EDGES) return;
    int d = (e < N_EDGES) ? ei[N_EDGES + e] : e - N_EDGES;
    atomicAdd(&deg[d], 1);
}

__global__ __launch_bounds__(256)
void scan1(const int* __restrict__ deg, int* __restrict__ bsum)
{
    __shared__ int s[256];
    int i = blockIdx.x * 256 + threadIdx.x;
    s[threadIdx.x] = (i < N_NODES) ? deg[i] : 0;
    __syncthreads();
    for (int off = 128; off > 0; off >>= 1) {
        if (threadIdx.x < off) s[threadIdx.x] += s[threadIdx.x + off];
        __syncthreads();
    }
    if (threadIdx.x == 0) bsum[blockIdx.x] = s[0];
}

__global__ void scan2(int* __restrict__ bsum)
{
    if (threadIdx.x == 0) {
        int acc = 0;
        for (int i = 0; i < NBLK; ++i) { int t = bsum[i]; bsum[i] = acc; acc += t; }
    }
}

__global__ __launch_bounds__(256)
void scan3(const int* __restrict__ deg, const int* __restrict__ bsum,
           int* __restrict__ rowptr, int* __restrict__ cursor)
{
    __shared__ int s[256];
    int i = blockIdx.x * 256 + threadIdx.x;
    int v = (i < N_NODES) ? deg[i] : 0;
    s[threadIdx.x] = v;
    __syncthreads();
    for (int off = 1; off < 256; off <<= 1) {
        int t = (threadIdx.x >= off) ? s[threadIdx.x - off] : 0;
        __syncthreads();
        s[threadIdx.x] += t;
        __syncthreads();
    }
    if (i < N_NODES) {
        int excl = s[threadIdx.x] - v + bsum[blockIdx.x];
        rowptr[i] = excl;
        cursor[i] = excl;
    }
    if (i == 0) rowptr[N_NODES] = ET_EDGES;
}

__global__ __launch_bounds__(256)
void edge_fill(const int* __restrict__ ei, int* __restrict__ cursor,
               int* __restrict__ csr_src)
{
    int e = blockIdx.x * 256 + threadIdx.x;
    if (e >= ET_EDGES) return;
    int s, d;
    if (e < N_EDGES) { s = ei[e]; d = ei[N_EDGES + e]; }
    else             { s = d = e - N_EDGES; }
    int pos = atomicAdd(&cursor[d], 1);
    csr_src[pos] = s;
}

// ---------------- GEMM + alpha epilogue (32 rows/block, 8 rows/thread) ------
// h output is bf16 (halves gather traffic downstream).
template<int CIN, bool DYN>
__global__ __launch_bounds__(256)
void gemm_alpha(const void* __restrict__ x,
                const float* __restrict__ W,
                const float* __restrict__ a_src,
                const float* __restrict__ a_dst,
                const unsigned* __restrict__ flag,
                bf16* __restrict__ hb,
                float* __restrict__ as_out,
                float* __restrict__ ad_out)
{
    __shared__ float sW[CIN * 64];
    __shared__ float sx[32 * CIN];
    const bool isbf = DYN ? (*flag != 0u) : false;
    const int tid = threadIdx.x;
    const int col = tid & 63;
    const int wv  = tid >> 6;
    const int row0 = blockIdx.x * 32;

    for (int i = tid * 4; i < CIN * 64; i += 1024)
        *(float4*)&sW[i] = *(const float4*)&W[i];

    const long xbase = (long)row0 * CIN;
    const int  tile  = 32 * CIN;
    const int  limit = (N_NODES - row0) * CIN;   // multiple of 4
    if (DYN && isbf) {
        const unsigned short* xb = (const unsigned short*)x + xbase;
        for (int i = tid * 4; i < tile; i += 1024) {
            float4 v = {0.f, 0.f, 0.f, 0.f};
            if (i < limit) {
                ushort4 u = *(const ushort4*)&xb[i];
                v.x = bfbits(u.x); v.y = bfbits(u.y);
                v.z = bfbits(u.z); v.w = bfbits(u.w);
            }
            *(float4*)&sx[i] = v;
        }
    } else {
        const float* xf = (const float*)x + xbase;
        for (int i = tid * 4; i < tile; i += 1024) {
            float4 v = {0.f, 0.f, 0.f, 0.f};
            if (i < limit) v = *(const float4*)&xf[i];
            *(float4*)&sx[i] = v;
        }
    }
    __syncthreads();

    const int rbase = wv * 8;
    float acc[8];
#pragma unroll
    for (int r = 0; r < 8; ++r) acc[r] = 0.f;

#pragma unroll 2
    for (int kk = 0; kk < CIN; kk += 4) {
        float w0 = sW[(kk + 0) * 64 + col];
        float w1 = sW[(kk + 1) * 64 + col];
        float w2 = sW[(kk + 2) * 64 + col];
        float w3 = sW[(kk + 3) * 64 + col];
#pragma unroll
        for (int r = 0; r < 8; ++r) {
            const float4 xv = *(const float4*)&sx[(rbase + r) * CIN + kk];
            acc[r] = fmaf(xv.x, w0,
                     fmaf(xv.y, w1,
                     fmaf(xv.z, w2,
                     fmaf(xv.w, w3, acc[r]))));
        }
    }

    const float sa = a_src[col];
    const float sd = a_dst[col];
#pragma unroll
    for (int r = 0; r < 8; ++r) {
        int row = row0 + rbase + r;
        float vs = acc[r] * sa;
        float vd = acc[r] * sd;
#pragma unroll
        for (int off = 32; off > 0; off >>= 1) {
            vs += __shfl_xor(vs, off, 64);
            vd += __shfl_xor(vd, off, 64);
        }
        if (row < N_NODES) {
            hb[(long)row * 64 + col] = __float2bfloat16(acc[r]);
            if (col == 0) { as_out[row] = vs; ad_out[row] = vd; }
        }
    }
}

// ---------------- Fused GAT gather ----------------
// Phase 1: one wave per node, lanes over edges, shuffle max/sum (no atomics).
// Phase 2: lane=(sub,c): sub in [0,4) picks edge, c in [0,16) loads 4 bf16
// channels as uint2 -> 4 edges per iteration, 4x fewer loads, half the bytes.
template<bool DO_ELU, bool OUT_DYN>
__global__ __launch_bounds__(256)
void gat_gather(const int* __restrict__ rowptr,
                const int* __restrict__ csr_src,
                const float* __restrict__ as_,
                const float* __restrict__ ad_,
                const unsigned short* __restrict__ hb,
                const float* __restrict__ bias,
                void* __restrict__ out,
                const unsigned* __restrict__ flag)
{
    int node = blockIdx.x * 4 + (threadIdx.x >> 6);
    if (node >= N_NODES) return;
    int lane = threadIdx.x & 63;
    int beg = rowptr[node];
    int deg = rowptr[node + 1] - beg;
    float adv = ad_[node];

    // ---- phase 1: scores, max, exp-sum ----
    int   my_src = 0;
    float my_e   = -1e30f;
    if (lane < deg) {
        my_src = csr_src[beg + lane];
        float v = as_[my_src] + adv;
        my_e = (v > 0.f) ? v : NEG_SLOPE * v;
    }
    float m = my_e;
    for (int j = 64 + lane; j < deg; j += 64) {
        int s2 = csr_src[beg + j];
        float v = as_[s2] + adv;
        v = (v > 0.f) ? v : NEG_SLOPE * v;
        m = fmaxf(m, v);
    }
#pragma unroll
    for (int off = 32; off > 0; off >>= 1) m = fmaxf(m, __shfl_xor(m, off, 64));

    float w = (lane < deg) ? __expf(my_e - m) : 0.f;
    float dsum = w;
    for (int j = 64 + lane; j < deg; j += 64) {
        int s2 = csr_src[beg + j];
        float v = as_[s2] + adv;
        v = (v > 0.f) ? v : NEG_SLOPE * v;
        dsum += __expf(v - m);
    }
#pragma unroll
    for (int off = 32; off > 0; off >>= 1) dsum += __shfl_xor(dsum, off, 64);
    float inv = 1.f / dsum;

    // ---- phase 2: 4 edges / iteration, bf16 h rows ----
    const int sub = lane >> 4;
    const int c4  = (lane & 15) * 4;
    float a0 = 0.f, a1 = 0.f, a2 = 0.f, a3 = 0.f;
    int dmin = (deg < 64) ? deg : 64;
    for (int j0 = 0; j0 < dmin; j0 += 4) {
        int j = j0 + sub;
        float wj = __shfl(w, j, 64);
        int   sj = __shfl(my_src, j, 64);
        if (j < dmin) {
            const uint2 p = *(const uint2*)&hb[(long)sj * 64 + c4];
            a0 = fmaf(wj, bflo(p.x), a0);
            a1 = fmaf(wj, bfhi(p.x), a1);
            a2 = fmaf(wj, bflo(p.y), a2);
            a3 = fmaf(wj, bfhi(p.y), a3);
        }
    }
    for (int j0 = 64; j0 < deg; j0 += 4) {     // rare (deg > 64)
        int j = j0 + sub;
        if (j < deg) {
            int sj = csr_src[beg + j];
            float v = as_[sj] + adv;
            v = (v > 0.f) ? v : NEG_SLOPE * v;
            float wj = __expf(v - m);
            const uint2 p = *(const uint2*)&hb[(long)sj * 64 + c4];
            a0 = fmaf(wj, bflo(p.x), a0);
            a1 = fmaf(wj, bfhi(p.x), a1);
            a2 = fmaf(wj, bflo(p.y), a2);
            a3 = fmaf(wj, bfhi(p.y), a3);
        }
    }
    // combine the 4 sub-groups (xor 16, 32)
#pragma unroll
    for (int off = 16; off < 64; off <<= 1) {
        a0 += __shfl_xor(a0, off, 64);
        a1 += __shfl_xor(a1, off, 64);
        a2 += __shfl_xor(a2, off, 64);
        a3 += __shfl_xor(a3, off, 64);
    }

    if (sub == 0) {   // lanes 0..15 hold channels c4..c4+3
        float r0 = a0 * inv + bias[c4 + 0];
        float r1 = a1 * inv + bias[c4 + 1];
        float r2 = a2 * inv + bias[c4 + 2];
        float r3 = a3 * inv + bias[c4 + 3];
        if (DO_ELU) {
            r0 = (r0 > 0.f) ? r0 : expm1f(r0);
            r1 = (r1 > 0.f) ? r1 : expm1f(r1);
            r2 = (r2 > 0.f) ? r2 : expm1f(r2);
            r3 = (r3 > 0.f) ? r3 : expm1f(r3);
        }
        long o = (long)node * 64 + c4;
        if (OUT_DYN && *flag != 0u) {
            ushort4 u;
            u.x = __bfloat16_as_ushort(__float2bfloat16(r0));
            u.y = __bfloat16_as_ushort(__float2bfloat16(r1));
            u.z = __bfloat16_as_ushort(__float2bfloat16(r2));
            u.w = __bfloat16_as_ushort(__float2bfloat16(r3));
            *(ushort4*)&((unsigned short*)out)[o] = u;
        } else {
            float4 r = {r0, r1, r2, r3};
            *(float4*)&((float*)out)[o] = r;
        }
    }
}

extern "C" void kernel_launch(void* const* d_in, const int* in_sizes, int n_in,
                              void* d_out, int out_size, void* d_ws, size_t ws_size,
                              hipStream_t stream)
{
    const void* x  = d_in[0];
    const int*  ei = (const int*)d_in[1];
    const void* pW1 = d_in[2],  *pas1 = d_in[3],  *pad1 = d_in[4],  *pb1 = d_in[5];
    const void* pW2 = d_in[6],  *pas2 = d_in[7],  *pad2 = d_in[8],  *pb2 = d_in[9];
    const void* pW3 = d_in[10], *pas3 = d_in[11], *pad3 = d_in[12], *pb3 = d_in[13];

    float* ws = (float*)d_ws;
    float*    bufA   = ws;                          // h as bf16 (uses half)
    float*    bufB   = bufA + (long)N_NODES * 64;   // layer io fp32     12.8 MB
    float*    as_    = bufB + (long)N_NODES * 64;
    float*    ad_    = as_ + N_NODES;
    int*      deg    = (int*)(ad_ + N_NODES);
    int*      rowptr = deg + N_NODES;
    int*      cursor = rowptr + N_NODES + 1;
    int*      bsum   = cursor + N_NODES;
    int*      csr_src= bsum + NBLK;
    float*    prm    = (float*)(csr_src + ET_EDGES);
    unsigned* flag   = (unsigned*)(prm + 20000);
    bf16*     hb     = (bf16*)bufA;

    float* W1 = prm;     float* as1 = W1 + 8192; float* ad1 = as1 + 64; float* b1 = ad1 + 64;
    float* W2 = b1 + 64; float* as2 = W2 + 4096; float* ad2 = as2 + 64; float* b2 = ad2 + 64;
    float* W3 = b2 + 64; float* as3 = W3 + 4096; float* ad3 = as3 + 64; float* b3 = ad3 + 64;

    detect_dtype<<<1, 64, 0, stream>>>((const unsigned short*)pW1, flag);

    CvtArgs ca;
    const void* srcs[12] = {pW1, pas1, pad1, pb1, pW2, pas2, pad2, pb2, pW3, pas3, pad3, pb3};
    float*      dsts[12] = {W1, as1, ad1, b1, W2, as2, ad2, b2, W3, as3, ad3, b3};
    int         ns[12]   = {8192, 64, 64, 64, 4096, 64, 64, 64, 4096, 64, 64, 64};
    for (int i = 0; i < 12; ++i) { ca.src[i] = srcs[i]; ca.dst[i] = dsts[i]; ca.n[i] = ns[i]; }
    convert_params<<<dim3(8, 12), 256, 0, stream>>>(ca, flag);

    // ---- CSR build (once per launch, shared by all 3 layers) ----
    const int edge_grid = (ET_EDGES + 255) / 256;
    hipMemsetAsync(deg, 0, (size_t)N_NODES * 4, stream);
    edge_hist<<<edge_grid, 256, 0, stream>>>(ei, deg);
    scan1<<<NBLK, 256, 0, stream>>>(deg, bsum);
    scan2<<<1, 64, 0, stream>>>(bsum);
    scan3<<<NBLK, 256, 0, stream>>>(deg, bsum, rowptr, cursor);
    edge_fill<<<edge_grid, 256, 0, stream>>>(ei, cursor, csr_src);

    const int gemm_grid = (N_NODES + 31) / 32;
    const int gat_grid  = (N_NODES + 3) / 4;

    // ---------- Layer 1 ----------
    gemm_alpha<128, true><<<gemm_grid, 256, 0, stream>>>(
        x, W1, as1, ad1, flag, hb, as_, ad_);
    gat_gather<true, false><<<gat_grid, 256, 0, stream>>>(
        rowptr, csr_src, as_, ad_, (const unsigned short*)hb, b1, bufB, flag);

    // ---------- Layer 2 ----------
    gemm_alpha<64, false><<<gemm_grid, 256, 0, stream>>>(
        bufB, W2, as2, ad2, flag, hb, as_, ad_);
    gat_gather<true, false><<<gat_grid, 256, 0, stream>>>(
        rowptr, csr_src, as_, ad_, (const unsigned short*)hb, b2, bufB, flag);

    // ---------- Layer 3 ----------
    gemm_alpha<64, false><<<gemm_grid, 256, 0, stream>>>(
        bufB, W3, as3, ad3, flag, hb, as_, ad_);
    gat_gather<false, true><<<gat_grid, 256, 0, stream>>>(
        rowptr, csr_src, as_, ad_, (const unsigned short*)hb, b3, d_out, flag);
}

// Round 7
// 377.031 us; speedup vs baseline: 2.5401x; 1.0035x over previous
//
#include <hip/hip_runtime.h>
#include <hip/hip_bf16.h>
#include <math.h>

#define N_NODES 50000
#define N_EDGES 800000
#define ET_EDGES (N_EDGES + N_NODES)   // with self-loops
#define CH 64
#define NEG_SLOPE 0.2f
#define NBLK ((N_NODES + 255) / 256)   // 196 scan blocks
#define NBUCK ((N_NODES + 255) / 256)  // 196 dst buckets (256 nodes each)
#define CHUNK 4096                      // edges per binning block

typedef __hip_bfloat16 bf16;

__device__ inline float bfbits(unsigned short u) {
    return __uint_as_float(((unsigned)u) << 16);
}
__device__ inline float bflo(unsigned u) { return __uint_as_float(u << 16); }
__device__ inline float bfhi(unsigned u) { return __uint_as_float(u & 0xffff0000u); }

// ---------------- dtype detection ----------------
__global__ void detect_dtype(const unsigned short* __restrict__ w1raw,
                             unsigned* __restrict__ flag)
{
    int t = threadIdx.x;
    float v0 = bfbits(w1raw[2 * t]);
    float v1 = bfbits(w1raw[2 * t + 1]);
    bool bad = !(fabsf(v0) <= 64.f && fabsf(v1) <= 64.f);  // NaN -> bad
    unsigned long long b = __ballot(bad);
    if (t == 0) *flag = (b == 0ull) ? 1u : 0u;
}

// ---------------- param conversion (12 small tensors -> fp32) ----------------
struct CvtArgs {
    const void* src[12];
    float*      dst[12];
    int         n[12];
};

__global__ __launch_bounds__(256)
void convert_params(CvtArgs a, const unsigned* __restrict__ flag)
{
    bool isbf = (*flag != 0u);
    int which = blockIdx.y;
    int n = a.n[which];
    const void* s = a.src[which];
    float* d = a.dst[which];
    for (int i = blockIdx.x * 256 + threadIdx.x; i < n; i += gridDim.x * 256) {
        d[i] = isbf ? bfbits(((const unsigned short*)s)[i])
                    : ((const float*)s)[i];
    }
}

// ---------------- CSR build: degree histogram + rowptr scan ----------------
__global__ __launch_bounds__(256)
void edge_hist(const int* __restrict__ ei, int* __restrict__ deg)
{
    int e = blockIdx.x * 256 + threadIdx.x;
    if (e >= ET_EDGES) return;
    int d = (e < N_EDGES) ? ei[N_EDGES + e] : e - N_EDGES;
    atomicAdd(&deg[d], 1);
}

__global__ __launch_bounds__(256)
void scan1(const int* __restrict__ deg, int* __restrict__ bsum)
{
    __shared__ int s[256];
    int i = blockIdx.x * 256 + threadIdx.x;
    s[threadIdx.x] = (i < N_NODES) ? deg[i] : 0;
    __syncthreads();
    for (int off = 128; off > 0; off >>= 1) {
        if (threadIdx.x < off) s[threadIdx.x] += s[threadIdx.x + off];
        __syncthreads();
    }
    if (threadIdx.x == 0) bsum[blockIdx.x] = s[0];
}

__global__ void scan2(int* __restrict__ bsum)
{
    if (threadIdx.x == 0) {
        int acc = 0;
        for (int i = 0; i < NBLK; ++i) { int t = bsum[i]; bsum[i] = acc; acc += t; }
    }
}

__global__ __launch_bounds__(256)
void scan3(const int* __restrict__ deg, const int* __restrict__ bsum,
           int* __restrict__ rowptr)
{
    __shared__ int s[256];
    int i = blockIdx.x * 256 + threadIdx.x;
    int v = (i < N_NODES) ? deg[i] : 0;
    s[threadIdx.x] = v;
    __syncthreads();
    for (int off = 1; off < 256; off <<= 1) {
        int t = (threadIdx.x >= off) ? s[threadIdx.x - off] : 0;
        __syncthreads();
        s[threadIdx.x] += t;
        __syncthreads();
    }
    if (i < N_NODES) rowptr[i] = s[threadIdx.x] - v + bsum[blockIdx.x];
    if (i == 0) rowptr[N_NODES] = ET_EDGES;
}

// bucket cursors start at the bucket's base offset in the CSR layout
__global__ void init_cur(const int* __restrict__ rowptr, int* __restrict__ cur256)
{
    int b = threadIdx.x;
    if (b < NBUCK) cur256[b] = rowptr[b * 256];
}

// ---------------- Pass C: bin edges by dst bucket into scratch --------------
// Entries packed (src<<8)|(dst&255); flushed bucket-sorted -> coalesced writes.
__global__ __launch_bounds__(256)
void binpass(const int* __restrict__ ei, int* __restrict__ cur256,
             unsigned* __restrict__ scratch)
{
    __shared__ int hist[NBUCK];
    __shared__ int lpre[NBUCK + 1];
    __shared__ int lcur[NBUCK];
    __shared__ int gbase[NBUCK];
    __shared__ int scan_a[256];
    __shared__ unsigned entry[CHUNK];

    const int tid = threadIdx.x;
    const int e0  = blockIdx.x * CHUNK;
    const int n   = min(CHUNK, ET_EDGES - e0);

    if (tid < NBUCK) hist[tid] = 0;
    __syncthreads();

    // 1) local histogram
    for (int k = tid; k < n; k += 256) {
        int e = e0 + k;
        int d = (e < N_EDGES) ? ei[N_EDGES + e] : e - N_EDGES;
        atomicAdd(&hist[d >> 8], 1);
    }
    __syncthreads();

    // 2) exclusive prefix over buckets (Hillis-Steele on 256)
    int v = (tid < NBUCK) ? hist[tid] : 0;
    scan_a[tid] = v;
    __syncthreads();
    for (int off = 1; off < 256; off <<= 1) {
        int t = (tid >= off) ? scan_a[tid - off] : 0;
        __syncthreads();
        scan_a[tid] += t;
        __syncthreads();
    }
    if (tid < NBUCK) lpre[tid] = scan_a[tid] - v;
    if (tid == NBUCK - 1) lpre[NBUCK] = scan_a[tid];
    // 3) reserve global ranges
    if (tid < NBUCK) {
        gbase[tid] = v ? atomicAdd(&cur256[tid], v) : 0;
        lcur[tid] = 0;
    }
    __syncthreads();

    // 4) LDS scatter into bucket-sorted order
    for (int k = tid; k < n; k += 256) {
        int e = e0 + k;
        int s, d;
        if (e < N_EDGES) { s = ei[e]; d = ei[N_EDGES + e]; }
        else             { s = d = e - N_EDGES; }
        int b = d >> 8;
        int p = atomicAdd(&lcur[b], 1);
        entry[lpre[b] + p] = ((unsigned)s << 8) | (unsigned)(d & 255);
    }
    __syncthreads();

    // 5) flush: consecutive i -> consecutive global positions within runs
    for (int i = tid; i < n; i += 256) {
        int lo = 0, hi = NBUCK;              // lpre[lo] <= i < lpre[hi]
        while (hi - lo > 1) {
            int mid = (lo + hi) >> 1;
            if (lpre[mid] <= i) lo = mid; else hi = mid;
        }
        scratch[gbase[lo] + (i - lpre[lo])] = entry[i];
    }
}

// ---------------- Pass D: fine scatter within each bucket -------------------
// One block per bucket; LDS cursors; all csr writes land in ~17KB window.
__global__ __launch_bounds__(256)
void fine_scatter(const int* __restrict__ rowptr,
                  const unsigned* __restrict__ scratch,
                  int* __restrict__ csr_src)
{
    __shared__ int lcur[256];
    const int tid = threadIdx.x;
    const int b   = blockIdx.x;
    const int nb  = b * 256;
    const int nn  = min(256, N_NODES - nb);
    if (tid < nn) lcur[tid] = rowptr[nb + tid];
    const int gb  = rowptr[nb];
    const int ge  = rowptr[nb + nn];
    __syncthreads();
    for (int i = gb + tid; i < ge; i += 256) {
        unsigned v = scratch[i];
        int p = atomicAdd(&lcur[v & 255u], 1);
        csr_src[p] = (int)(v >> 8);
    }
}

// ---------------- GEMM + alpha epilogue (32 rows/block, 8 rows/thread) ------
template<int CIN, bool DYN>
__global__ __launch_bounds__(256)
void gemm_alpha(const void* __restrict__ x,
                const float* __restrict__ W,
                const float* __restrict__ a_src,
                const float* __restrict__ a_dst,
                const unsigned* __restrict__ flag,
                bf16* __restrict__ hb,
                float* __restrict__ as_out,
                float* __restrict__ ad_out)
{
    __shared__ float sW[CIN * 64];
    __shared__ float sx[32 * CIN];
    const bool isbf = DYN ? (*flag != 0u) : false;
    const int tid = threadIdx.x;
    const int col = tid & 63;
    const int wv  = tid >> 6;
    const int row0 = blockIdx.x * 32;

    for (int i = tid * 4; i < CIN * 64; i += 1024)
        *(float4*)&sW[i] = *(const float4*)&W[i];

    const long xbase = (long)row0 * CIN;
    const int  tile  = 32 * CIN;
    const int  limit = (N_NODES - row0) * CIN;   // multiple of 4
    if (DYN && isbf) {
        const unsigned short* xb = (const unsigned short*)x + xbase;
        for (int i = tid * 4; i < tile; i += 1024) {
            float4 v = {0.f, 0.f, 0.f, 0.f};
            if (i < limit) {
                ushort4 u = *(const ushort4*)&xb[i];
                v.x = bfbits(u.x); v.y = bfbits(u.y);
                v.z = bfbits(u.z); v.w = bfbits(u.w);
            }
            *(float4*)&sx[i] = v;
        }
    } else {
        const float* xf = (const float*)x + xbase;
        for (int i = tid * 4; i < tile; i += 1024) {
            float4 v = {0.f, 0.f, 0.f, 0.f};
            if (i < limit) v = *(const float4*)&xf[i];
            *(float4*)&sx[i] = v;
        }
    }
    __syncthreads();

    const int rbase = wv * 8;
    float acc[8];
#pragma unroll
    for (int r = 0; r < 8; ++r) acc[r] = 0.f;

#pragma unroll 2
    for (int kk = 0; kk < CIN; kk += 4) {
        float w0 = sW[(kk + 0) * 64 + col];
        float w1 = sW[(kk + 1) * 64 + col];
        float w2 = sW[(kk + 2) * 64 + col];
        float w3 = sW[(kk + 3) * 64 + col];
#pragma unroll
        for (int r = 0; r < 8; ++r) {
            const float4 xv = *(const float4*)&sx[(rbase + r) * CIN + kk];
            acc[r] = fmaf(xv.x, w0,
                     fmaf(xv.y, w1,
                     fmaf(xv.z, w2,
                     fmaf(xv.w, w3, acc[r]))));
        }
    }

    const float sa = a_src[col];
    const float sd = a_dst[col];
#pragma unroll
    for (int r = 0; r < 8; ++r) {
        int row = row0 + rbase + r;
        float vs = acc[r] * sa;
        float vd = acc[r] * sd;
#pragma unroll
        for (int off = 32; off > 0; off >>= 1) {
            vs += __shfl_xor(vs, off, 64);
            vd += __shfl_xor(vd, off, 64);
        }
        if (row < N_NODES) {
            hb[(long)row * 64 + col] = __float2bfloat16(acc[r]);
            if (col == 0) { as_out[row] = vs; ad_out[row] = vd; }
        }
    }
}

// ---------------- Fused GAT gather ----------------
// Phase 1: one wave per node, lanes over edges, shuffle max/sum.
// Phase 2: lane=(sub8,cg8): 8 edges/iter, each row read by 8 lanes x uint4.
template<bool DO_ELU, bool OUT_DYN>
__global__ __launch_bounds__(256)
void gat_gather(const int* __restrict__ rowptr,
                const int* __restrict__ csr_src,
                const float* __restrict__ as_,
                const float* __restrict__ ad_,
                const unsigned short* __restrict__ hb,
                const float* __restrict__ bias,
                void* __restrict__ out,
                const unsigned* __restrict__ flag)
{
    int node = blockIdx.x * 4 + (threadIdx.x >> 6);
    if (node >= N_NODES) return;
    int lane = threadIdx.x & 63;
    int beg = rowptr[node];
    int deg = rowptr[node + 1] - beg;
    float adv = ad_[node];

    // ---- phase 1: scores, max, exp-sum ----
    int   my_src = 0;
    float my_e   = -1e30f;
    if (lane < deg) {
        my_src = csr_src[beg + lane];
        float v = as_[my_src] + adv;
        my_e = (v > 0.f) ? v : NEG_SLOPE * v;
    }
    float m = my_e;
    for (int j = 64 + lane; j < deg; j += 64) {
        int s2 = csr_src[beg + j];
        float v = as_[s2] + adv;
        v = (v > 0.f) ? v : NEG_SLOPE * v;
        m = fmaxf(m, v);
    }
#pragma unroll
    for (int off = 32; off > 0; off >>= 1) m = fmaxf(m, __shfl_xor(m, off, 64));

    float w = (lane < deg) ? __expf(my_e - m) : 0.f;
    float dsum = w;
    for (int j = 64 + lane; j < deg; j += 64) {
        int s2 = csr_src[beg + j];
        float v = as_[s2] + adv;
        v = (v > 0.f) ? v : NEG_SLOPE * v;
        dsum += __expf(v - m);
    }
#pragma unroll
    for (int off = 32; off > 0; off >>= 1) dsum += __shfl_xor(dsum, off, 64);
    float inv = 1.f / dsum;

    // ---- phase 2: 8 edges / iteration, bf16 h rows (uint4 = 8 ch) ----
    const int sub = lane >> 3;       // edge slot 0..7
    const int c8  = (lane & 7) * 8;  // channel group
    float a0 = 0.f, a1 = 0.f, a2 = 0.f, a3 = 0.f;
    float a4 = 0.f, a5 = 0.f, a6 = 0.f, a7 = 0.f;
    int dmin = (deg < 64) ? deg : 64;
    for (int j0 = 0; j0 < dmin; j0 += 8) {
        int j = j0 + sub;
        float wj = __shfl(w, j, 64);
        int   sj = __shfl(my_src, j, 64);
        if (j < dmin) {
            const uint4 p = *(const uint4*)&hb[(long)sj * 64 + c8];
            a0 = fmaf(wj, bflo(p.x), a0);
            a1 = fmaf(wj, bfhi(p.x), a1);
            a2 = fmaf(wj, bflo(p.y), a2);
            a3 = fmaf(wj, bfhi(p.y), a3);
            a4 = fmaf(wj, bflo(p.z), a4);
            a5 = fmaf(wj, bfhi(p.z), a5);
            a6 = fmaf(wj, bflo(p.w), a6);
            a7 = fmaf(wj, bfhi(p.w), a7);
        }
    }
    for (int j0 = 64; j0 < deg; j0 += 8) {     // rare (deg > 64)
        int j = j0 + sub;
        if (j < deg) {
            int sj = csr_src[beg + j];
            float v = as_[sj] + adv;
            v = (v > 0.f) ? v : NEG_SLOPE * v;
            float wj = __expf(v - m);
            const uint4 p = *(const uint4*)&hb[(long)sj * 64 + c8];
            a0 = fmaf(wj, bflo(p.x), a0);
            a1 = fmaf(wj, bfhi(p.x), a1);
            a2 = fmaf(wj, bflo(p.y), a2);
            a3 = fmaf(wj, bfhi(p.y), a3);
            a4 = fmaf(wj, bflo(p.z), a4);
            a5 = fmaf(wj, bfhi(p.z), a5);
            a6 = fmaf(wj, bflo(p.w), a6);
            a7 = fmaf(wj, bfhi(p.w), a7);
        }
    }
    // combine the 8 sub-groups (xor 8,16,32)
#pragma unroll
    for (int off = 8; off < 64; off <<= 1) {
        a0 += __shfl_xor(a0, off, 64);
        a1 += __shfl_xor(a1, off, 64);
        a2 += __shfl_xor(a2, off, 64);
        a3 += __shfl_xor(a3, off, 64);
        a4 += __shfl_xor(a4, off, 64);
        a5 += __shfl_xor(a5, off, 64);
        a6 += __shfl_xor(a6, off, 64);
        a7 += __shfl_xor(a7, off, 64);
    }

    if (sub == 0) {   // lanes 0..7 hold channels c8..c8+7
        float r[8] = {a0, a1, a2, a3, a4, a5, a6, a7};
#pragma unroll
        for (int k = 0; k < 8; ++k) {
            r[k] = r[k] * inv + bias[c8 + k];
            if (DO_ELU) r[k] = (r[k] > 0.f) ? r[k] : expm1f(r[k]);
        }
        long o = (long)node * 64 + c8;
        if (OUT_DYN && *flag != 0u) {
            ushort4 u0, u1;
            u0.x = __bfloat16_as_ushort(__float2bfloat16(r[0]));
            u0.y = __bfloat16_as_ushort(__float2bfloat16(r[1]));
            u0.z = __bfloat16_as_ushort(__float2bfloat16(r[2]));
            u0.w = __bfloat16_as_ushort(__float2bfloat16(r[3]));
            u1.x = __bfloat16_as_ushort(__float2bfloat16(r[4]));
            u1.y = __bfloat16_as_ushort(__float2bfloat16(r[5]));
            u1.z = __bfloat16_as_ushort(__float2bfloat16(r[6]));
            u1.w = __bfloat16_as_ushort(__float2bfloat16(r[7]));
            *(ushort4*)&((unsigned short*)out)[o]     = u0;
            *(ushort4*)&((unsigned short*)out)[o + 4] = u1;
        } else {
            float4 f0 = {r[0], r[1], r[2], r[3]};
            float4 f1 = {r[4], r[5], r[6], r[7]};
            *(float4*)&((float*)out)[o]     = f0;
            *(float4*)&((float*)out)[o + 4] = f1;
        }
    }
}

extern "C" void kernel_launch(void* const* d_in, const int* in_sizes, int n_in,
                              void* d_out, int out_size, void* d_ws, size_t ws_size,
                              hipStream_t stream)
{
    const void* x  = d_in[0];
    const int*  ei = (const int*)d_in[1];
    const void* pW1 = d_in[2],  *pas1 = d_in[3],  *pad1 = d_in[4],  *pb1 = d_in[5];
    const void* pW2 = d_in[6],  *pas2 = d_in[7],  *pad2 = d_in[8],  *pb2 = d_in[9];
    const void* pW3 = d_in[10], *pas3 = d_in[11], *pad3 = d_in[12], *pb3 = d_in[13];

    float* ws = (float*)d_ws;
    float*    bufA   = ws;                          // hb (bf16) in first half
    float*    bufB   = bufA + (long)N_NODES * 64;   // layer io fp32     12.8 MB
    float*    as_    = bufB + (long)N_NODES * 64;
    float*    ad_    = as_ + N_NODES;
    int*      deg    = (int*)(ad_ + N_NODES);
    int*      rowptr = deg + N_NODES;               // N+1
    int*      bsum   = rowptr + N_NODES + 1;        // NBLK
    int*      cur256 = bsum + NBLK;                 // NBUCK
    int*      csr_src= cur256 + NBUCK;              // 3.4 MB
    float*    prm    = (float*)(csr_src + ET_EDGES);
    unsigned* flag   = (unsigned*)(prm + 20000);
    bf16*     hb     = (bf16*)bufA;
    unsigned* scratch= (unsigned*)(bufA + (long)N_NODES * 32);  // upper half of bufA

    float* W1 = prm;     float* as1 = W1 + 8192; float* ad1 = as1 + 64; float* b1 = ad1 + 64;
    float* W2 = b1 + 64; float* as2 = W2 + 4096; float* ad2 = as2 + 64; float* b2 = ad2 + 64;
    float* W3 = b2 + 64; float* as3 = W3 + 4096; float* ad3 = as3 + 64; float* b3 = ad3 + 64;

    detect_dtype<<<1, 64, 0, stream>>>((const unsigned short*)pW1, flag);

    CvtArgs ca;
    const void* srcs[12] = {pW1, pas1, pad1, pb1, pW2, pas2, pad2, pb2, pW3, pas3, pad3, pb3};
    float*      dsts[12] = {W1, as1, ad1, b1, W2, as2, ad2, b2, W3, as3, ad3, b3};
    int         ns[12]   = {8192, 64, 64, 64, 4096, 64, 64, 64, 4096, 64, 64, 64};
    for (int i = 0; i < 12; ++i) { ca.src[i] = srcs[i]; ca.dst[i] = dsts[i]; ca.n[i] = ns[i]; }
    convert_params<<<dim3(8, 12), 256, 0, stream>>>(ca, flag);

    // ---- CSR build: hist -> rowptr -> bucket-binned two-pass scatter ----
    const int edge_grid = (ET_EDGES + 255) / 256;
    hipMemsetAsync(deg, 0, (size_t)N_NODES * 4, stream);
    edge_hist<<<edge_grid, 256, 0, stream>>>(ei, deg);
    scan1<<<NBLK, 256, 0, stream>>>(deg, bsum);
    scan2<<<1, 64, 0, stream>>>(bsum);
    scan3<<<NBLK, 256, 0, stream>>>(deg, bsum, rowptr);
    init_cur<<<1, 256, 0, stream>>>(rowptr, cur256);
    binpass<<<(ET_EDGES + CHUNK - 1) / CHUNK, 256, 0, stream>>>(ei, cur256, scratch);
    fine_scatter<<<NBUCK, 256, 0, stream>>>(rowptr, scratch, csr_src);

    const int gemm_grid = (N_NODES + 31) / 32;
    const int gat_grid  = (N_NODES + 3) / 4;

    // ---------- Layer 1 ----------
    gemm_alpha<128, true><<<gemm_grid, 256, 0, stream>>>(
        x, W1, as1, ad1, flag, hb, as_, ad_);
    gat_gather<true, false><<<gat_grid, 256, 0, stream>>>(
        rowptr, csr_src, as_, ad_, (const unsigned short*)hb, b1, bufB, flag);

    // ---------- Layer 2 ----------
    gemm_alpha<64, false><<<gemm_grid, 256, 0, stream>>>(
        bufB, W2, as2, ad2, flag, hb, as_, ad_);
    gat_gather<true, false><<<gat_grid, 256, 0, stream>>>(
        rowptr, csr_src, as_, ad_, (const unsigned short*)hb, b2, bufB, flag);

    // ---------- Layer 3 ----------
    gemm_alpha<64, false><<<gemm_grid, 256, 0, stream>>>(
        bufB, W3, as3, ad3, flag, hb, as_, ad_);
    gat_gather<false, true><<<gat_grid, 256, 0, stream>>>(
        rowptr, csr_src, as_, ad_, (const unsigned short*)hb, b3, d_out, flag);
}

// Round 8
// 340.173 us; speedup vs baseline: 2.8153x; 1.1084x over previous
//
#include <hip/hip_runtime.h>
#include <hip/hip_bf16.h>
#include <math.h>

#define N_NODES 50000
#define N_EDGES 800000
#define ET_EDGES (N_EDGES + N_NODES)   // with self-loops
#define CH 64
#define NEG_SLOPE 0.2f
#define NBLK ((N_NODES + 255) / 256)   // 196 scan blocks
#define NBUCK ((N_NODES + 255) / 256)  // 196 dst buckets (256 nodes each)
#define CHUNK 4096                      // edges per binning block

typedef __hip_bfloat16 bf16;

__device__ inline float bfbits(unsigned short u) {
    return __uint_as_float(((unsigned)u) << 16);
}
__device__ inline float bflo(unsigned u) { return __uint_as_float(u << 16); }
__device__ inline float bfhi(unsigned u) { return __uint_as_float(u & 0xffff0000u); }

// ---------------- dtype detection ----------------
__global__ void detect_dtype(const unsigned short* __restrict__ w1raw,
                             unsigned* __restrict__ flag)
{
    int t = threadIdx.x;
    float v0 = bfbits(w1raw[2 * t]);
    float v1 = bfbits(w1raw[2 * t + 1]);
    bool bad = !(fabsf(v0) <= 64.f && fabsf(v1) <= 64.f);  // NaN -> bad
    unsigned long long b = __ballot(bad);
    if (t == 0) *flag = (b == 0ull) ? 1u : 0u;
}

// ---------------- param conversion (12 small tensors -> fp32) ----------------
struct CvtArgs {
    const void* src[12];
    float*      dst[12];
    int         n[12];
};

__global__ __launch_bounds__(256)
void convert_params(CvtArgs a, const unsigned* __restrict__ flag)
{
    bool isbf = (*flag != 0u);
    int which = blockIdx.y;
    int n = a.n[which];
    const void* s = a.src[which];
    float* d = a.dst[which];
    for (int i = blockIdx.x * 256 + threadIdx.x; i < n; i += gridDim.x * 256) {
        d[i] = isbf ? bfbits(((const unsigned short*)s)[i])
                    : ((const float*)s)[i];
    }
}

// ---------------- CSR build: degree histogram + rowptr scan ----------------
__global__ __launch_bounds__(256)
void edge_hist(const int* __restrict__ ei, int* __restrict__ deg)
{
    int e = blockIdx.x * 256 + threadIdx.x;
    if (e >= ET_EDGES) return;
    int d = (e < N_EDGES) ? ei[N_EDGES + e] : e - N_EDGES;
    atomicAdd(&deg[d], 1);
}

__global__ __launch_bounds__(256)
void scan1(const int* __restrict__ deg, int* __restrict__ bsum)
{
    __shared__ int s[256];
    int i = blockIdx.x * 256 + threadIdx.x;
    s[threadIdx.x] = (i < N_NODES) ? deg[i] : 0;
    __syncthreads();
    for (int off = 128; off > 0; off >>= 1) {
        if (threadIdx.x < off) s[threadIdx.x] += s[threadIdx.x + off];
        __syncthreads();
    }
    if (threadIdx.x == 0) bsum[blockIdx.x] = s[0];
}

// parallel single-block exclusive scan over NBLK block sums (was serial 1-thread)
__global__ __launch_bounds__(256)
void scan2(int* __restrict__ bsum)
{
    __shared__ int s[256];
    int t = threadIdx.x;
    int v = (t < NBLK) ? bsum[t] : 0;
    s[t] = v;
    __syncthreads();
    for (int off = 1; off < 256; off <<= 1) {
        int u = (t >= off) ? s[t - off] : 0;
        __syncthreads();
        s[t] += u;
        __syncthreads();
    }
    if (t < NBLK) bsum[t] = s[t] - v;   // exclusive
}

__global__ __launch_bounds__(256)
void scan3(const int* __restrict__ deg, const int* __restrict__ bsum,
           int* __restrict__ rowptr, int* __restrict__ cur256)
{
    __shared__ int s[256];
    int i = blockIdx.x * 256 + threadIdx.x;
    int v = (i < N_NODES) ? deg[i] : 0;
    s[threadIdx.x] = v;
    __syncthreads();
    for (int off = 1; off < 256; off <<= 1) {
        int t = (threadIdx.x >= off) ? s[threadIdx.x - off] : 0;
        __syncthreads();
        s[threadIdx.x] += t;
        __syncthreads();
    }
    if (i < N_NODES) {
        int excl = s[threadIdx.x] - v + bsum[blockIdx.x];
        rowptr[i] = excl;
        if (threadIdx.x == 0) cur256[blockIdx.x] = excl;  // bucket cursor base
    }
    if (i == 0) rowptr[N_NODES] = ET_EDGES;
}

// ---------------- Pass C: bin edges by dst bucket into scratch --------------
// Entries packed (src<<8)|(dst&255); flushed bucket-sorted -> coalesced writes.
__global__ __launch_bounds__(256)
void binpass(const int* __restrict__ ei, int* __restrict__ cur256,
             unsigned* __restrict__ scratch)
{
    __shared__ int hist[NBUCK];
    __shared__ int lpre[NBUCK + 1];
    __shared__ int lcur[NBUCK];
    __shared__ int gbase[NBUCK];
    __shared__ int scan_a[256];
    __shared__ unsigned entry[CHUNK];

    const int tid = threadIdx.x;
    const int e0  = blockIdx.x * CHUNK;
    const int n   = min(CHUNK, ET_EDGES - e0);

    if (tid < NBUCK) hist[tid] = 0;
    __syncthreads();

    for (int k = tid; k < n; k += 256) {
        int e = e0 + k;
        int d = (e < N_EDGES) ? ei[N_EDGES + e] : e - N_EDGES;
        atomicAdd(&hist[d >> 8], 1);
    }
    __syncthreads();

    int v = (tid < NBUCK) ? hist[tid] : 0;
    scan_a[tid] = v;
    __syncthreads();
    for (int off = 1; off < 256; off <<= 1) {
        int t = (tid >= off) ? scan_a[tid - off] : 0;
        __syncthreads();
        scan_a[tid] += t;
        __syncthreads();
    }
    if (tid < NBUCK) lpre[tid] = scan_a[tid] - v;
    if (tid == NBUCK - 1) lpre[NBUCK] = scan_a[tid];
    if (tid < NBUCK) {
        gbase[tid] = v ? atomicAdd(&cur256[tid], v) : 0;
        lcur[tid] = 0;
    }
    __syncthreads();

    for (int k = tid; k < n; k += 256) {
        int e = e0 + k;
        int s, d;
        if (e < N_EDGES) { s = ei[e]; d = ei[N_EDGES + e]; }
        else             { s = d = e - N_EDGES; }
        int b = d >> 8;
        int p = atomicAdd(&lcur[b], 1);
        entry[lpre[b] + p] = ((unsigned)s << 8) | (unsigned)(d & 255);
    }
    __syncthreads();

    for (int i = tid; i < n; i += 256) {
        int lo = 0, hi = NBUCK;
        while (hi - lo > 1) {
            int mid = (lo + hi) >> 1;
            if (lpre[mid] <= i) lo = mid; else hi = mid;
        }
        scratch[gbase[lo] + (i - lpre[lo])] = entry[i];
    }
}

// ---------------- Pass D: fine scatter within each bucket -------------------
__global__ __launch_bounds__(256)
void fine_scatter(const int* __restrict__ rowptr,
                  const unsigned* __restrict__ scratch,
                  int* __restrict__ csr_src)
{
    __shared__ int lcur[256];
    const int tid = threadIdx.x;
    const int b   = blockIdx.x;
    const int nb  = b * 256;
    const int nn  = min(256, N_NODES - nb);
    if (tid < nn) lcur[tid] = rowptr[nb + tid];
    const int gb  = rowptr[nb];
    const int ge  = rowptr[nb + nn];
    __syncthreads();
    for (int i = gb + tid; i < ge; i += 256) {
        unsigned v = scratch[i];
        int p = atomicAdd(&lcur[v & 255u], 1);
        csr_src[p] = (int)(v >> 8);
    }
}

// ---------------- GEMM + alpha epilogue (32 rows/block, 8 rows/thread) ------
template<int CIN, bool DYN>
__global__ __launch_bounds__(256)
void gemm_alpha(const void* __restrict__ x,
                const float* __restrict__ W,
                const float* __restrict__ a_src,
                const float* __restrict__ a_dst,
                const unsigned* __restrict__ flag,
                bf16* __restrict__ hb,
                float* __restrict__ as_out,
                float* __restrict__ ad_out)
{
    __shared__ float sW[CIN * 64];
    __shared__ float sx[32 * CIN];
    const bool isbf = DYN ? (*flag != 0u) : false;
    const int tid = threadIdx.x;
    const int col = tid & 63;
    const int wv  = tid >> 6;
    const int row0 = blockIdx.x * 32;

    for (int i = tid * 4; i < CIN * 64; i += 1024)
        *(float4*)&sW[i] = *(const float4*)&W[i];

    const long xbase = (long)row0 * CIN;
    const int  tile  = 32 * CIN;
    const int  limit = (N_NODES - row0) * CIN;   // multiple of 4
    if (DYN && isbf) {
        const unsigned short* xb = (const unsigned short*)x + xbase;
        for (int i = tid * 4; i < tile; i += 1024) {
            float4 v = {0.f, 0.f, 0.f, 0.f};
            if (i < limit) {
                ushort4 u = *(const ushort4*)&xb[i];
                v.x = bfbits(u.x); v.y = bfbits(u.y);
                v.z = bfbits(u.z); v.w = bfbits(u.w);
            }
            *(float4*)&sx[i] = v;
        }
    } else {
        const float* xf = (const float*)x + xbase;
        for (int i = tid * 4; i < tile; i += 1024) {
            float4 v = {0.f, 0.f, 0.f, 0.f};
            if (i < limit) v = *(const float4*)&xf[i];
            *(float4*)&sx[i] = v;
        }
    }
    __syncthreads();

    const int rbase = wv * 8;
    float acc[8];
#pragma unroll
    for (int r = 0; r < 8; ++r) acc[r] = 0.f;

#pragma unroll 2
    for (int kk = 0; kk < CIN; kk += 4) {
        float w0 = sW[(kk + 0) * 64 + col];
        float w1 = sW[(kk + 1) * 64 + col];
        float w2 = sW[(kk + 2) * 64 + col];
        float w3 = sW[(kk + 3) * 64 + col];
#pragma unroll
        for (int r = 0; r < 8; ++r) {
            const float4 xv = *(const float4*)&sx[(rbase + r) * CIN + kk];
            acc[r] = fmaf(xv.x, w0,
                     fmaf(xv.y, w1,
                     fmaf(xv.z, w2,
                     fmaf(xv.w, w3, acc[r]))));
        }
    }

    const float sa = a_src[col];
    const float sd = a_dst[col];
#pragma unroll
    for (int r = 0; r < 8; ++r) {
        int row = row0 + rbase + r;
        float vs = acc[r] * sa;
        float vd = acc[r] * sd;
#pragma unroll
        for (int off = 32; off > 0; off >>= 1) {
            vs += __shfl_xor(vs, off, 64);
            vd += __shfl_xor(vd, off, 64);
        }
        if (row < N_NODES) {
            hb[(long)row * 64 + col] = __float2bfloat16(acc[r]);
            if (col == 0) { as_out[row] = vs; ad_out[row] = vd; }
        }
    }
}

// ---------------- Fused GAT gather: 16-lane group per node ------------------
// 4 nodes/wave, 16/block. Phase 1: 16 lanes over edges, 4-level shuffle
// reductions. Phase 2: sub in {0,1} picks edge, 8 lanes x uint4 = 8 bf16 ch.
// deg>16 tail recomputes exp (Poisson(17) tail, ~15% of edges).
template<bool DO_ELU, bool OUT_DYN>
__global__ __launch_bounds__(256)
void gat_gather(const int* __restrict__ rowptr,
                const int* __restrict__ csr_src,
                const float* __restrict__ as_,
                const float* __restrict__ ad_,
                const unsigned short* __restrict__ hb,
                const float* __restrict__ bias,
                void* __restrict__ out,
                const unsigned* __restrict__ flag)
{
    const int tid   = threadIdx.x;
    const int lane  = tid & 63;
    const int l16   = lane & 15;
    const int gb16  = lane & 48;                    // group base within wave
    const int node  = blockIdx.x * 16 + (tid >> 4); // 16 nodes per block

    int beg = 0, deg = 0;
    float adv = 0.f;
    if (node < N_NODES) {
        beg = rowptr[node];
        deg = rowptr[node + 1] - beg;
        adv = ad_[node];
    }

    // ---- phase 1: scores, max, exp-sum (first 16 edges in registers) ----
    int   my_src = 0;
    float my_e   = -1e30f;
    if (l16 < deg) {
        my_src = csr_src[beg + l16];
        float v = as_[my_src] + adv;
        my_e = (v > 0.f) ? v : NEG_SLOPE * v;
    }
    float m = my_e;
    for (int j = 16 + l16; j < deg; j += 16) {
        int s2 = csr_src[beg + j];
        float v = as_[s2] + adv;
        v = (v > 0.f) ? v : NEG_SLOPE * v;
        m = fmaxf(m, v);
    }
#pragma unroll
    for (int off = 8; off > 0; off >>= 1) m = fmaxf(m, __shfl_xor(m, off, 64));

    float w = (l16 < deg) ? __expf(my_e - m) : 0.f;
    float dsum = w;
    for (int j = 16 + l16; j < deg; j += 16) {
        int s2 = csr_src[beg + j];
        float v = as_[s2] + adv;
        v = (v > 0.f) ? v : NEG_SLOPE * v;
        dsum += __expf(v - m);
    }
#pragma unroll
    for (int off = 8; off > 0; off >>= 1) dsum += __shfl_xor(dsum, off, 64);
    float inv = 1.f / dsum;

    // ---- phase 2: 2 edges / group-iteration, uint4 = 8 bf16 ch ----
    const int sub = l16 >> 3;        // edge slot 0/1
    const int c8  = (l16 & 7) * 8;   // channel group
    float a0 = 0.f, a1 = 0.f, a2 = 0.f, a3 = 0.f;
    float a4 = 0.f, a5 = 0.f, a6 = 0.f, a7 = 0.f;
    const int dmin = (deg < 16) ? deg : 16;
    for (int j0 = 0; j0 < dmin; j0 += 2) {
        int j = j0 + sub;
        float wj = __shfl(w, gb16 + j, 64);
        int   sj = __shfl(my_src, gb16 + j, 64);
        if (j < dmin) {
            const uint4 p = *(const uint4*)&hb[(long)sj * 64 + c8];
            a0 = fmaf(wj, bflo(p.x), a0);
            a1 = fmaf(wj, bfhi(p.x), a1);
            a2 = fmaf(wj, bflo(p.y), a2);
            a3 = fmaf(wj, bfhi(p.y), a3);
            a4 = fmaf(wj, bflo(p.z), a4);
            a5 = fmaf(wj, bfhi(p.z), a5);
            a6 = fmaf(wj, bflo(p.w), a6);
            a7 = fmaf(wj, bfhi(p.w), a7);
        }
    }
    for (int j0 = 16; j0 < deg; j0 += 2) {   // tail: recompute exp
        int j = j0 + sub;
        if (j < deg) {
            int sj = csr_src[beg + j];
            float v = as_[sj] + adv;
            v = (v > 0.f) ? v : NEG_SLOPE * v;
            float wj = __expf(v - m);
            const uint4 p = *(const uint4*)&hb[(long)sj * 64 + c8];
            a0 = fmaf(wj, bflo(p.x), a0);
            a1 = fmaf(wj, bfhi(p.x), a1);
            a2 = fmaf(wj, bflo(p.y), a2);
            a3 = fmaf(wj, bfhi(p.y), a3);
            a4 = fmaf(wj, bflo(p.z), a4);
            a5 = fmaf(wj, bfhi(p.z), a5);
            a6 = fmaf(wj, bflo(p.w), a6);
            a7 = fmaf(wj, bfhi(p.w), a7);
        }
    }
    // combine the two edge slots
    a0 += __shfl_xor(a0, 8, 64);
    a1 += __shfl_xor(a1, 8, 64);
    a2 += __shfl_xor(a2, 8, 64);
    a3 += __shfl_xor(a3, 8, 64);
    a4 += __shfl_xor(a4, 8, 64);
    a5 += __shfl_xor(a5, 8, 64);
    a6 += __shfl_xor(a6, 8, 64);
    a7 += __shfl_xor(a7, 8, 64);

    if (sub == 0 && node < N_NODES) {   // lanes l16 0..7 hold ch c8..c8+7
        float r[8] = {a0, a1, a2, a3, a4, a5, a6, a7};
#pragma unroll
        for (int k = 0; k < 8; ++k) {
            r[k] = r[k] * inv + bias[c8 + k];
            if (DO_ELU) r[k] = (r[k] > 0.f) ? r[k] : expm1f(r[k]);
        }
        long o = (long)node * 64 + c8;
        if (OUT_DYN && *flag != 0u) {
            uint4 u;
            u.x = ((unsigned)__bfloat16_as_ushort(__float2bfloat16(r[0]))) |
                  (((unsigned)__bfloat16_as_ushort(__float2bfloat16(r[1]))) << 16);
            u.y = ((unsigned)__bfloat16_as_ushort(__float2bfloat16(r[2]))) |
                  (((unsigned)__bfloat16_as_ushort(__float2bfloat16(r[3]))) << 16);
            u.z = ((unsigned)__bfloat16_as_ushort(__float2bfloat16(r[4]))) |
                  (((unsigned)__bfloat16_as_ushort(__float2bfloat16(r[5]))) << 16);
            u.w = ((unsigned)__bfloat16_as_ushort(__float2bfloat16(r[6]))) |
                  (((unsigned)__bfloat16_as_ushort(__float2bfloat16(r[7]))) << 16);
            *(uint4*)&((unsigned short*)out)[o] = u;
        } else {
            float4 f0 = {r[0], r[1], r[2], r[3]};
            float4 f1 = {r[4], r[5], r[6], r[7]};
            *(float4*)&((float*)out)[o]     = f0;
            *(float4*)&((float*)out)[o + 4] = f1;
        }
    }
}

extern "C" void kernel_launch(void* const* d_in, const int* in_sizes, int n_in,
                              void* d_out, int out_size, void* d_ws, size_t ws_size,
                              hipStream_t stream)
{
    const void* x  = d_in[0];
    const int*  ei = (const int*)d_in[1];
    const void* pW1 = d_in[2],  *pas1 = d_in[3],  *pad1 = d_in[4],  *pb1 = d_in[5];
    const void* pW2 = d_in[6],  *pas2 = d_in[7],  *pad2 = d_in[8],  *pb2 = d_in[9];
    const void* pW3 = d_in[10], *pas3 = d_in[11], *pad3 = d_in[12], *pb3 = d_in[13];

    float* ws = (float*)d_ws;
    float*    bufA   = ws;                          // hb (bf16) lower half
    float*    bufB   = bufA + (long)N_NODES * 64;   // layer io fp32     12.8 MB
    float*    as_    = bufB + (long)N_NODES * 64;
    float*    ad_    = as_ + N_NODES;
    int*      deg    = (int*)(ad_ + N_NODES);
    int*      rowptr = deg + N_NODES;               // N+1
    int*      bsum   = rowptr + N_NODES + 1;        // NBLK
    int*      cur256 = bsum + NBLK;                 // NBUCK
    int*      csr_src= cur256 + NBUCK;              // 3.4 MB
    float*    prm    = (float*)(csr_src + ET_EDGES);
    unsigned* flag   = (unsigned*)(prm + 20000);
    bf16*     hb     = (bf16*)bufA;
    unsigned* scratch= (unsigned*)(bufA + (long)N_NODES * 32);  // upper half of bufA

    float* W1 = prm;     float* as1 = W1 + 8192; float* ad1 = as1 + 64; float* b1 = ad1 + 64;
    float* W2 = b1 + 64; float* as2 = W2 + 4096; float* ad2 = as2 + 64; float* b2 = ad2 + 64;
    float* W3 = b2 + 64; float* as3 = W3 + 4096; float* ad3 = as3 + 64; float* b3 = ad3 + 64;

    detect_dtype<<<1, 64, 0, stream>>>((const unsigned short*)pW1, flag);

    CvtArgs ca;
    const void* srcs[12] = {pW1, pas1, pad1, pb1, pW2, pas2, pad2, pb2, pW3, pas3, pad3, pb3};
    float*      dsts[12] = {W1, as1, ad1, b1, W2, as2, ad2, b2, W3, as3, ad3, b3};
    int         ns[12]   = {8192, 64, 64, 64, 4096, 64, 64, 64, 4096, 64, 64, 64};
    for (int i = 0; i < 12; ++i) { ca.src[i] = srcs[i]; ca.dst[i] = dsts[i]; ca.n[i] = ns[i]; }
    convert_params<<<dim3(8, 12), 256, 0, stream>>>(ca, flag);

    // ---- CSR build: hist -> rowptr -> bucket-binned two-pass scatter ----
    const int edge_grid = (ET_EDGES + 255) / 256;
    hipMemsetAsync(deg, 0, (size_t)N_NODES * 4, stream);
    edge_hist<<<edge_grid, 256, 0, stream>>>(ei, deg);
    scan1<<<NBLK, 256, 0, stream>>>(deg, bsum);
    scan2<<<1, 256, 0, stream>>>(bsum);
    scan3<<<NBLK, 256, 0, stream>>>(deg, bsum, rowptr, cur256);
    binpass<<<(ET_EDGES + CHUNK - 1) / CHUNK, 256, 0, stream>>>(ei, cur256, scratch);
    fine_scatter<<<NBUCK, 256, 0, stream>>>(rowptr, scratch, csr_src);

    const int gemm_grid = (N_NODES + 31) / 32;
    const int gat_grid  = (N_NODES + 15) / 16;

    // ---------- Layer 1 ----------
    gemm_alpha<128, true><<<gemm_grid, 256, 0, stream>>>(
        x, W1, as1, ad1, flag, hb, as_, ad_);
    gat_gather<true, false><<<gat_grid, 256, 0, stream>>>(
        rowptr, csr_src, as_, ad_, (const unsigned short*)hb, b1, bufB, flag);

    // ---------- Layer 2 ----------
    gemm_alpha<64, false><<<gemm_grid, 256, 0, stream>>>(
        bufB, W2, as2, ad2, flag, hb, as_, ad_);
    gat_gather<true, false><<<gat_grid, 256, 0, stream>>>(
        rowptr, csr_src, as_, ad_, (const unsigned short*)hb, b2, bufB, flag);

    // ---------- Layer 3 ----------
    gemm_alpha<64, false><<<gemm_grid, 256, 0, stream>>>(
        bufB, W3, as3, ad3, flag, hb, as_, ad_);
    gat_gather<false, true><<<gat_grid, 256, 0, stream>>>(
        rowptr, csr_src, as_, ad_, (const unsigned short*)hb, b3, d_out, flag);
}